// Round 9
// baseline (803.560 us; speedup 1.0000x reference)
//
#include <hip/hip_runtime.h>
#include <math.h>

#define H 128
#define EDGES 500000
#define NFACT 100000
#define NCOMP 5000
#define BATCH 64
#define NTILE 6250   // NFACT/16

typedef _Float16 half8_t __attribute__((ext_vector_type(8)));
typedef float floatx4 __attribute__((ext_vector_type(4)));

__device__ inline short4 f4_to_h4(float4 v){
  union { short4 s; _Float16 h[4]; } u;
  u.h[0]=(_Float16)v.x; u.h[1]=(_Float16)v.y; u.h[2]=(_Float16)v.z; u.h[3]=(_Float16)v.w;
  return u.s;
}

// ----------------- CSR build -----------------
__global__ __launch_bounds__(1024) void k_scan1(const int* __restrict__ cnt, int n,
                                                int* __restrict__ offs, int* __restrict__ part){
  __shared__ int sh[1024];
  int tid = threadIdx.x;
  int i = blockIdx.x*1024 + tid;
  int v = (i < n) ? cnt[i] : 0;
  sh[tid] = v;
  __syncthreads();
  for (int d = 1; d < 1024; d <<= 1){
    int t = (tid >= d) ? sh[tid-d] : 0;
    __syncthreads();
    sh[tid] += t;
    __syncthreads();
  }
  if (i < n) offs[i] = sh[tid] - v;
  if (tid == 1023) part[blockIdx.x] = sh[1023];
}

__global__ void k_scan2(int* part, int nb){
  __shared__ int sh[128];
  int tid = threadIdx.x;
  int v = (tid < nb) ? part[tid] : 0;
  sh[tid] = v;
  __syncthreads();
  for (int d = 1; d < 128; d <<= 1){
    int t = (tid >= d) ? sh[tid-d] : 0;
    __syncthreads();
    sh[tid] += t;
    __syncthreads();
  }
  if (tid < nb) part[tid] = sh[tid] - v;
}

__global__ __launch_bounds__(1024) void k_scan3(int* offs, int n, const int* __restrict__ part, int total){
  int i = blockIdx.x*1024 + threadIdx.x;
  if (i < n) offs[i] += part[blockIdx.x];
  if (i == 0) offs[n] = total;
}

// both directions in one launch, block-uniform direction split
__global__ void k_fill2d(const int* __restrict__ src0, const int* __restrict__ dst0,
                         const float* __restrict__ w0, const int* __restrict__ offs0,
                         int* __restrict__ cur0, int4* __restrict__ ed0,
                         const int* __restrict__ src1, const int* __restrict__ dst1,
                         const float* __restrict__ w1, const int* __restrict__ offs1,
                         int* __restrict__ cur1, int4* __restrict__ ed1, int n){
  int half = gridDim.x >> 1;
  int dir = blockIdx.x >= half;
  const int* src = dir ? src1 : src0;
  const int* dst = dir ? dst1 : dst0;
  const float* w = dir ? w1 : w0;
  const int* offs = dir ? offs1 : offs0;
  int* cur = dir ? cur1 : cur0;
  int4* ed = dir ? ed1 : ed0;
  int bid = blockIdx.x - (dir ? half : 0);
  for (int e = bid*blockDim.x + threadIdx.x; e < n; e += half*blockDim.x){
    int d = dst[e];
    int p = offs[d] + atomicAdd(&cur[d], 1);
    ed[p] = make_int4(src[e], __float_as_int(w[e]), d, 0);
  }
}

// ----------------- weight prep: f16 transposed copies -----------------
__global__ __launch_bounds__(256) void k_prep(const float* __restrict__ W_in,
                                              const float* __restrict__ W_rel,
                                              const float* __restrict__ W_root,
                                              _Float16* __restrict__ wt_in,
                                              _Float16* __restrict__ wcat0,
                                              _Float16* __restrict__ wcat1){
  int i = blockIdx.x*256 + threadIdx.x;
  if (i < 49152){
    int n = i / 384, k = i % 384;
    wt_in[i] = (_Float16)W_in[k*128 + n];
  } else if (i < 49152 + 32768){
    int j = i - 49152;
    int n = j / 256, k = j % 256;
    const float* Wr = W_rel  + 1*16384;
    const float* Wo = W_root + 1*16384;
    wcat0[j] = (_Float16)(k < 128 ? Wr[k*128+n] : Wo[(k-128)*128+n]);
  } else if (i < 49152 + 65536){
    int j = i - 49152 - 32768;
    int n = j / 256, k = j % 256;
    const float* Wr = W_rel  + 3*16384;
    const float* Wo = W_root + 3*16384;
    wcat1[j] = (_Float16)(k < 128 ? Wr[k*128+n] : Wo[(k-128)*128+n]);
  }
}

// ----------------- edge gate MLP + histogram (fused, R7-proven) -------------
__global__ __launch_bounds__(256) void k_gate2(const float* __restrict__ ea0,
                       const float* __restrict__ ea1,
                       const int* __restrict__ dst0, const int* __restrict__ dst1,
                       int* __restrict__ cnt0, int* __restrict__ cnt1,
                       const float* __restrict__ eW1, const float* __restrict__ eb1,
                       const float* __restrict__ eW2, const float* __restrict__ eb2,
                       const float* __restrict__ eW3, const float* __restrict__ eb3,
                       float* __restrict__ wout0, float* __restrict__ wout1, int n){
  __shared__ float w1t[32*12];   // transposed + padded: w1t[i][k] = eW1[k*32+i]
  __shared__ float w2s[32*16];
  __shared__ float b1s[32], b2s[16], w3s[16];
  __shared__ float b3s;
  int tid = threadIdx.x;
  for (int i = tid; i < 352; i += 256){
    int k = i >> 5, c = i & 31;
    w1t[c*12 + k] = eW1[i];
  }
  if (tid < 32) w1t[tid*12 + 11] = 0.f;
  for (int i = tid; i < 512; i += 256) w2s[i] = eW2[i];
  if (tid < 32) b1s[tid] = eb1[tid];
  if (tid < 16) b2s[tid] = eb2[tid];
  if (tid < 16) w3s[tid] = eW3[tid];
  if (tid == 0) b3s = eb3[0];
  __syncthreads();

  int half = gridDim.x >> 1;
  int dir = blockIdx.x >= half;
  const float* ea = dir ? ea1 : ea0;
  const int* dst  = dir ? dst1 : dst0;
  int* cnt        = dir ? cnt1 : cnt0;
  float* wout     = dir ? wout1 : wout0;
  int bid = blockIdx.x - (dir ? half : 0);

  const float4* w1t4 = (const float4*)w1t;
  const float4* w24  = (const float4*)w2s;
  float4 b2v0 = ((const float4*)b2s)[0], b2v1 = ((const float4*)b2s)[1];
  float4 b2v2 = ((const float4*)b2s)[2], b2v3 = ((const float4*)b2s)[3];
  float4 w3v0 = ((const float4*)w3s)[0], w3v1 = ((const float4*)w3s)[1];
  float4 w3v2 = ((const float4*)w3s)[2], w3v3 = ((const float4*)w3s)[3];

  for (int e = bid*blockDim.x + tid; e < n; e += half*blockDim.x){
    float2 eav = ((const float2*)ea)[e];
    float sent  = fminf(fmaxf(eav.x, -1.f), 1.f);
    float decay = eav.y;
    float dt = fmaxf(-__logf(fmaxf(decay, 1e-6f)) * 100.f, 0.f);
    float ds = fminf(dt * (1.f/30.f), 12.f);
    float s1 = __sinf(ds), c1 = __cosf(ds);
    float s2v = 2.f*s1*c1;
    float c2v = 1.f - 2.f*s1*s1;
    float s3v = s1*c2v + c1*s2v;
    float c3v = c1*c2v - s1*s2v;
    float s4v = 2.f*s2v*c2v;
    float c4v = 1.f - 2.f*s2v*s2v;
    // x padded to 12 in three named float4s (pad slot = 0, matches w1t pad)
    float4 x0 = make_float4(sent, __logf(1.f + dt), s1, s2v);
    float4 x1 = make_float4(s3v, s4v, c1, c2v);
    float4 x2 = make_float4(c3v, c4v, ds, 0.f);

    float4 sa = b2v0, sb = b2v1, sc = b2v2, sd = b2v3;
    #pragma unroll 2
    for (int i = 0; i < 32; i++){
      float4 wa = w1t4[i*3+0], wb = w1t4[i*3+1], wc = w1t4[i*3+2];
      float h = b1s[i];
      h += x0.x*wa.x + x0.y*wa.y + x0.z*wa.z + x0.w*wa.w;
      h += x1.x*wb.x + x1.y*wb.y + x1.z*wb.z + x1.w*wb.w;
      h += x2.x*wc.x + x2.y*wc.y + x2.z*wc.z;
      h = fmaxf(h, 0.f);
      float4 va = w24[i*4+0], vb = w24[i*4+1], vc = w24[i*4+2], vd = w24[i*4+3];
      sa.x += h*va.x; sa.y += h*va.y; sa.z += h*va.z; sa.w += h*va.w;
      sb.x += h*vb.x; sb.y += h*vb.y; sb.z += h*vb.z; sb.w += h*vb.w;
      sc.x += h*vc.x; sc.y += h*vc.y; sc.z += h*vc.z; sc.w += h*vc.w;
      sd.x += h*vd.x; sd.y += h*vd.y; sd.z += h*vd.z; sd.w += h*vd.w;
    }
    float o = b3s;
    o += fmaxf(sa.x,0.f)*w3v0.x + fmaxf(sa.y,0.f)*w3v0.y + fmaxf(sa.z,0.f)*w3v0.z + fmaxf(sa.w,0.f)*w3v0.w;
    o += fmaxf(sb.x,0.f)*w3v1.x + fmaxf(sb.y,0.f)*w3v1.y + fmaxf(sb.z,0.f)*w3v1.z + fmaxf(sb.w,0.f)*w3v1.w;
    o += fmaxf(sc.x,0.f)*w3v2.x + fmaxf(sc.y,0.f)*w3v2.y + fmaxf(sc.z,0.f)*w3v2.z + fmaxf(sc.w,0.f)*w3v2.w;
    o += fmaxf(sd.x,0.f)*w3v3.x + fmaxf(sd.y,0.f)*w3v3.y + fmaxf(sd.z,0.f)*w3v3.z + fmaxf(sd.w,0.f)*w3v3.w;
    wout[e] = __fdividef(1.f, 1.f + __expf(-o));
    atomicAdd(&cnt[dst[e]], 1);
  }
}

// ----------------- simple input projection (comp side, small) -----------------
template<int K, int R>
__global__ __launch_bounds__(128) void k_input_s(const float* __restrict__ X, const float* __restrict__ W,
                                                 const float* __restrict__ bias, float* __restrict__ Y){
  __shared__ float xs[R*K];
  int t = threadIdx.x;
  long row0 = (long)blockIdx.x * R;
  const float4* src = (const float4*)(X + row0*K);
  float4* d4 = (float4*)xs;
  for (int i = t; i < R*K/4; i += 128) d4[i] = src[i];
  __syncthreads();
  float acc[R];
  #pragma unroll
  for (int r = 0; r < R; r++) acc[r] = 0.f;
  for (int k4 = 0; k4 < K/4; k4++){
    int kb = k4*4;
    float w0 = W[(kb+0)*H+t], w1 = W[(kb+1)*H+t], w2 = W[(kb+2)*H+t], w3 = W[(kb+3)*H+t];
    #pragma unroll
    for (int r = 0; r < R; r++){
      float4 xv = ((const float4*)(xs + r*K))[k4];
      acc[r] += xv.x*w0 + xv.y*w1 + xv.z*w2 + xv.w*w3;
    }
  }
  float b = bias[t];
  #pragma unroll
  for (int r = 0; r < R; r++)
    Y[(row0+r)*H + t] = fmaxf(acc[r] + b, 0.f);
}

// ----------------- MFMA input projection v5 (R4-proven) ---------------------
__global__ __launch_bounds__(256, 2) void k_input_m(const float* __restrict__ X,
                                                 const _Float16* __restrict__ Wt,
                                                 const float* __restrict__ bias,
                                                 float* __restrict__ Y){
  __shared__ _Float16 xs[16][392];
  __shared__ float tb[4*16*36];    // per-wave transpose buffers
  int t = threadIdx.x;
  int lane = t & 63, wv = t >> 6;
  int m = lane & 15, q = lane >> 4;

  half8_t wreg[2][12];
  float bcol[2];
  #pragma unroll
  for (int j = 0; j < 2; j++){
    int col = (wv*2 + j)*16 + m;
    const _Float16* wb = Wt + (size_t)col*384 + q*8;
    #pragma unroll
    for (int ks = 0; ks < 12; ks++) wreg[j][ks] = *(const half8_t*)(wb + ks*32);
    bcol[j] = bias[col];
  }

  int row_i[6], c4_i[6];
  #pragma unroll
  for (int i = 0; i < 6; i++){
    int idx = i*256 + t;
    row_i[i] = idx/96; c4_i[i] = idx - row_i[i]*96;
  }

  int tpb = (NTILE + gridDim.x - 1)/gridDim.x;
  int tb0 = blockIdx.x*tpb, tb1 = tb0 + tpb;
  if (tb1 > NTILE) tb1 = NTILE;
  if (tb0 >= tb1) return;

  const float4* X4 = (const float4*)X;
  float4 r[6];
  #pragma unroll
  for (int i = 0; i < 6; i++) r[i] = X4[(size_t)tb0*1536 + i*256 + t];

  float* tbw = &tb[wv*576];
  int rowl = lane >> 2, c8l = lane & 3;

  for (int tile = tb0; tile < tb1; ++tile){
    __syncthreads();
    #pragma unroll
    for (int i = 0; i < 6; i++)
      *(short4*)&xs[row_i[i]][c4_i[i]*4] = f4_to_h4(r[i]);
    __syncthreads();
    if (tile + 1 < tb1){
      size_t base = (size_t)(tile+1)*1536;
      #pragma unroll
      for (int i = 0; i < 6; i++) r[i] = X4[base + i*256 + t];
    }
    __builtin_amdgcn_sched_barrier(0);

    floatx4 acc0 = (floatx4){0.f,0.f,0.f,0.f};
    floatx4 acc1 = (floatx4){0.f,0.f,0.f,0.f};
    #pragma unroll
    for (int ks = 0; ks < 12; ks++){
      half8_t av = *(const half8_t*)&xs[m][ks*32 + q*8];
      acc0 = __builtin_amdgcn_mfma_f32_16x16x32_f16(av, wreg[0][ks], acc0, 0, 0, 0);
      acc1 = __builtin_amdgcn_mfma_f32_16x16x32_f16(av, wreg[1][ks], acc1, 0, 0, 0);
    }
    long rb = (long)tile*16;
    #pragma unroll
    for (int j = 0; j < 2; j++){
      floatx4 a = j ? acc1 : acc0;
      int lc = j*16 + m;
      #pragma unroll
      for (int i2 = 0; i2 < 4; i2++)
        tbw[(q*4+i2)*36 + lc] = fmaxf(a[i2] + bcol[j], 0.f);
    }
    __syncthreads();
    {
      const float* srcp = tbw + rowl*36 + c8l*8;
      float* dstp = Y + (rb + rowl)*H + wv*32 + c8l*8;
      *(float4*)dstp       = *(const float4*)(srcp);
      *(float4*)(dstp + 4) = *(const float4*)(srcp + 4);
    }
  }
}

// ----------------- MFMA fused fact layer v3 ---------------------------------
// R8 post-mortem: LDS union (9.2KB) raised occupancy 20->26% but dur was
// UNCHANGED -> per-block serial latency chain is the limiter, not occupancy
// capacity. v3: (a) record prefetch — next 8-edge batch's ed[] loads issued
// before current batch's gathers, cutting the per-iter chain from 2 L2
// round-trips to ~1; (b) 4-wave blocks (4 independent 16-row tiles, private
// 9.2KB LDS partitions, NO barriers — intra-wave LDS is HW-in-order);
// (c) pad reverted 272->264 (R8 measured 272 worse: 800K vs 600K conflicts).
__global__ __launch_bounds__(256) void k_layer_m(
    const float* __restrict__ xsrc, const float* __restrict__ xprev,
    const int* __restrict__ offs, const int4* __restrict__ ed,
    const _Float16* __restrict__ Wt, const float* __restrict__ brel,
    const float* __restrict__ lnsc, const float* __restrict__ lnbi,
    float* __restrict__ xnext){
  __shared__ float tball[4*2304];    // 4 waves x 9216 B
  int t = threadIdx.x;
  int lane = t & 63, wv = t >> 6;
  long tile = (long)blockIdx.x*4 + wv;
  if (tile*16 >= NFACT) return;
  long row0 = tile*16;
  float* tb = tball + wv*2304;
  _Float16 (*xin)[264] = reinterpret_cast<_Float16 (*)[264]>(tb);
  int c = lane & 31, g = lane >> 5;
  int grow0 = g*8;
  #pragma unroll
  for (int j = 0; j < 8; j++){
    int lr = grow0 + j;
    ((short4*)&xin[lr][0])[c] = make_short4(0,0,0,0);
    float4 pv = ((const float4*)(xprev + (row0+lr)*H))[c];
    ((short4*)&xin[lr][128])[c] = f4_to_h4(pv);
  }
  int lo = offs[row0 + grow0], hi = offs[row0 + grow0 + 8];
  float4 a = make_float4(0.f,0.f,0.f,0.f);
  int cur = (int)row0 + grow0;
  int idx = lo;
  int nb = (hi - lo) >> 3;
  int4 rec[8];
  if (nb > 0){
    #pragma unroll
    for (int j = 0; j < 8; j++) rec[j] = ed[idx+j];
  }
  for (int b = 0; b < nb; b++){
    int nxt = idx + 8;
    int4 rec2[8];
    if (b + 1 < nb){
      #pragma unroll
      for (int j = 0; j < 8; j++) rec2[j] = ed[nxt+j];   // prefetch next batch
    }
    float4 v[8];
    #pragma unroll
    for (int j = 0; j < 8; j++) v[j] = ((const float4*)(xsrc + (long)rec[j].x*H))[c];
    #pragma unroll
    for (int j = 0; j < 8; j++){
      float w = __int_as_float(rec[j].y);
      if (rec[j].z != cur){ ((short4*)&xin[cur-(int)row0][0])[c] = f4_to_h4(a); a = make_float4(0.f,0.f,0.f,0.f); cur = rec[j].z; }
      a.x += v[j].x*w; a.y += v[j].y*w; a.z += v[j].z*w; a.w += v[j].w*w;
    }
    #pragma unroll
    for (int j = 0; j < 8; j++) rec[j] = rec2[j];
    idx = nxt;
  }
  for (; idx < hi; idx++){
    int4 mrec = ed[idx];
    float4 v = ((const float4*)(xsrc + (long)mrec.x*H))[c];
    float w = __int_as_float(mrec.y);
    if (mrec.z != cur){ ((short4*)&xin[cur-(int)row0][0])[c] = f4_to_h4(a); a = make_float4(0.f,0.f,0.f,0.f); cur = mrec.z; }
    a.x += v.x*w; a.y += v.y*w; a.z += v.z*w; a.w += v.w*w;
  }
  if (lo < hi) ((short4*)&xin[cur-(int)row0][0])[c] = f4_to_h4(a);

  int m = lane & 15, q = lane >> 4;
  floatx4 acc[8];
  #pragma unroll
  for (int nt = 0; nt < 8; nt++) acc[nt] = (floatx4){0.f,0.f,0.f,0.f};
  #pragma unroll
  for (int ks = 0; ks < 8; ks++){
    half8_t av = *(const half8_t*)&xin[m][ks*32 + q*8];
    #pragma unroll
    for (int nt = 0; nt < 8; nt++){
      half8_t bv = *(const half8_t*)(Wt + (size_t)(nt*16 + m)*256 + ks*32 + q*8);
      acc[nt] = __builtin_amdgcn_mfma_f32_16x16x32_f16(av, bv, acc[nt], 0, 0, 0);
    }
  }
  float vs[8][4];
  float s[4] = {0.f,0.f,0.f,0.f}, ss[4] = {0.f,0.f,0.f,0.f};
  #pragma unroll
  for (int nt = 0; nt < 8; nt++){
    int col = nt*16 + m;
    float b = brel[col];
    #pragma unroll
    for (int i = 0; i < 4; i++){
      int lr = q*4 + i;
      float pv = (float)xin[lr][128 + col];
      float v = fmaxf(acc[nt][i] + b, 0.f) + pv;
      vs[nt][i] = v;
      s[i] += v; ss[i] += v*v;
    }
  }
  #pragma unroll
  for (int i = 0; i < 4; i++){
    #pragma unroll
    for (int mm = 1; mm < 16; mm <<= 1){
      s[i]  += __shfl_xor(s[i],  mm, 64);
      ss[i] += __shfl_xor(ss[i], mm, 64);
    }
  }
  asm volatile("" ::: "memory");   // xin fully consumed -> reuse LDS as tb
  // LN -> LDS transpose tile
  #pragma unroll
  for (int nt = 0; nt < 8; nt++){
    int col = nt*16 + m;
    float lsc = lnsc[col], lbi = lnbi[col];
    int chnk = col >> 5, lc = col & 31;
    #pragma unroll
    for (int i = 0; i < 4; i++){
      float mu  = s[i]*(1.f/H);
      float var = ss[i]*(1.f/H) - mu*mu;
      float rstd = rsqrtf(var + 1e-5f);
      tb[(q*4+i)*144 + chnk*36 + lc] = (vs[nt][i] - mu)*rstd*lsc + lbi;
    }
  }
  asm volatile("" ::: "memory");
  // coalesced write-back: 4 lanes cover one full 512B row
  {
    int rowl = lane >> 2, c8 = lane & 3;
    const float* srcp = &tb[rowl*144 + c8*36];
    float4* dst4 = (float4*)(xnext + (row0 + rowl)*H + c8*32);
    #pragma unroll
    for (int k = 0; k < 8; k++)
      dst4[k] = *(const float4*)(srcp + k*4);
  }
}

// ----------------- fp32 fused layer (comp side), proven R4 config -----------
template<int R>
__global__ __launch_bounds__(128) void k_layer(
    const float* __restrict__ xsrc, const float* __restrict__ xprev,
    const int* __restrict__ offs, const int4* __restrict__ ed,
    const float* __restrict__ Wrel, const float* __restrict__ brel,
    const float* __restrict__ Wroot, const float* __restrict__ lnsc,
    const float* __restrict__ lnbi, float* __restrict__ xnext){
  constexpr int RG = R/4;
  __shared__ float xin[R][256];
  int t = threadIdx.x, c = t & 31, g = t >> 5;
  long row0 = (long)blockIdx.x * R;
  int grow0 = g*RG;
  #pragma unroll
  for (int j = 0; j < RG; j++){
    int lr = grow0 + j;
    ((float4*)&xin[lr][0])[c] = make_float4(0.f,0.f,0.f,0.f);
    ((float4*)&xin[lr][128])[c] = ((const float4*)(xprev + (row0+lr)*H))[c];
  }
  int lo = offs[row0 + grow0], hi = offs[row0 + grow0 + RG];
  float4 a = make_float4(0.f,0.f,0.f,0.f);
  int cur = (int)row0 + grow0;
  int idx = lo;
  for (; idx + 8 <= hi; idx += 8){
    int4 m[8];
    #pragma unroll
    for (int j = 0; j < 8; j++) m[j] = ed[idx+j];
    float4 v[8];
    #pragma unroll
    for (int j = 0; j < 8; j++) v[j] = ((const float4*)(xsrc + (long)m[j].x*H))[c];
    #pragma unroll
    for (int j = 0; j < 8; j++){
      float w = __int_as_float(m[j].y);
      if (m[j].z != cur){ ((float4*)&xin[cur-(int)row0][0])[c] = a; a = make_float4(0.f,0.f,0.f,0.f); cur = m[j].z; }
      a.x += v[j].x*w; a.y += v[j].y*w; a.z += v[j].z*w; a.w += v[j].w*w;
    }
  }
  for (; idx < hi; idx++){
    int4 m = ed[idx];
    float4 v = ((const float4*)(xsrc + (long)m.x*H))[c];
    float w = __int_as_float(m.y);
    if (m.z != cur){ ((float4*)&xin[cur-(int)row0][0])[c] = a; a = make_float4(0.f,0.f,0.f,0.f); cur = m.z; }
    a.x += v.x*w; a.y += v.y*w; a.z += v.z*w; a.w += v.w*w;
  }
  if (lo < hi) ((float4*)&xin[cur-(int)row0][0])[c] = a;

  float4 acc[RG];
  float4 bv = ((const float4*)brel)[c];
  #pragma unroll
  for (int j = 0; j < RG; j++) acc[j] = bv;
  #pragma unroll
  for (int p = 0; p < 2; p++){
    const float4* Wp = (const float4*)(p ? Wroot : Wrel) + c;
    #pragma unroll 4
    for (int k4 = 0; k4 < 32; k4++){
      float4 xv[RG];
      #pragma unroll
      for (int j = 0; j < RG; j++)
        xv[j] = ((const float4*)xin[grow0+j])[p*32 + k4];
      #pragma unroll
      for (int kk = 0; kk < 4; kk++){
        float4 wv = Wp[(size_t)(k4*4+kk)*32];
        #pragma unroll
        for (int j = 0; j < RG; j++){
          float xk = (kk==0) ? xv[j].x : (kk==1) ? xv[j].y : (kk==2) ? xv[j].z : xv[j].w;
          acc[j].x += xk*wv.x; acc[j].y += xk*wv.y; acc[j].z += xk*wv.z; acc[j].w += xk*wv.w;
        }
      }
    }
  }
  float4 lsc = ((const float4*)lnsc)[c];
  float4 lbi = ((const float4*)lnbi)[c];
  #pragma unroll
  for (int j = 0; j < RG; j++){
    int lr = grow0 + j;
    float4 pv = ((const float4*)&xin[lr][128])[c];
    float4 v;
    v.x = fmaxf(acc[j].x, 0.f) + pv.x;
    v.y = fmaxf(acc[j].y, 0.f) + pv.y;
    v.z = fmaxf(acc[j].z, 0.f) + pv.z;
    v.w = fmaxf(acc[j].w, 0.f) + pv.w;
    float s  = v.x + v.y + v.z + v.w;
    float ss = v.x*v.x + v.y*v.y + v.z*v.z + v.w*v.w;
    #pragma unroll
    for (int mm = 1; mm < 32; mm <<= 1){ s += __shfl_xor(s, mm, 64); ss += __shfl_xor(ss, mm, 64); }
    float mu  = s*(1.f/H);
    float var = ss*(1.f/H) - mu*mu;
    float rstd = rsqrtf(var + 1e-5f);
    float4 o;
    o.x = (v.x - mu)*rstd*lsc.x + lbi.x;
    o.y = (v.y - mu)*rstd*lsc.y + lbi.y;
    o.z = (v.z - mu)*rstd*lsc.z + lbi.z;
    o.w = (v.w - mu)*rstd*lsc.w + lbi.w;
    ((float4*)(xnext + (row0+lr)*H))[c] = o;
  }
}

// ----------------- pooling -----------------
#define PCHUNK 128
#define FBLK ((NFACT + PCHUNK - 1) / PCHUNK)
#define CBLK ((NCOMP + PCHUNK - 1) / PCHUNK)

__global__ __launch_bounds__(128) void k_pool_acc(const float* __restrict__ xf, const float* __restrict__ xc,
                                                  const int* __restrict__ fb, const int* __restrict__ cb,
                                                  float* __restrict__ pooled){
  int t = threadIdx.x;
  int b = blockIdx.x;
  if (b < FBLK){
    int start = b*PCHUNK, end = start + PCHUNK; if (end > NFACT) end = NFACT;
    float s = 0.f; int curb = -1;
    for (int i = start; i < end; i++){
      int bb = fb[i];
      if (bb != curb){
        if (curb >= 0) atomicAdd(&pooled[curb*256 + t], s);
        curb = bb; s = 0.f;
      }
      s += xf[(long)i*H + t];
    }
    if (curb >= 0) atomicAdd(&pooled[curb*256 + t], s);
  } else {
    int bbk = b - FBLK;
    int start = bbk*PCHUNK, end = start + PCHUNK; if (end > NCOMP) end = NCOMP;
    float s = 0.f; int curb = -1;
    for (int i = start; i < end; i++){
      int bb = cb[i];
      if (bb != curb){
        if (curb >= 0) atomicAdd(&pooled[curb*256 + 128 + t], s);
        curb = bb; s = 0.f;
      }
      s += xc[(long)i*H + t];
    }
    if (curb >= 0) atomicAdd(&pooled[curb*256 + 128 + t], s);
  }
}

// ----------------- classifier head -----------------
__device__ inline int lowerb(const int* a, int n, int key){
  int lo = 0, hi = n;
  while (lo < hi){ int m = (lo+hi) >> 1; if (a[m] < key) lo = m+1; else hi = m; }
  return lo;
}

__global__ __launch_bounds__(128) void k_head(const float* __restrict__ pooled,
                                              const int* __restrict__ fb, const int* __restrict__ cb,
                                              const float* __restrict__ Wc1, const float* __restrict__ bc1,
                                              const float* __restrict__ Wc2, const float* __restrict__ bc2,
                                              float* __restrict__ out){
  __shared__ float p[256];
  __shared__ float red[2];
  int t = threadIdx.x, b = blockIdx.x;
  int flo = lowerb(fb, NFACT, b), fhi = lowerb(fb, NFACT, b+1);
  int clo = lowerb(cb, NCOMP, b), chi = lowerb(cb, NCOMP, b+1);
  float fc = (float)((fhi - flo) > 1 ? (fhi - flo) : 1);
  float cc = (float)((chi - clo) > 1 ? (chi - clo) : 1);
  p[t]       = pooled[b*256 + t] / fc;
  p[128 + t] = pooled[b*256 + 128 + t] / cc;
  __syncthreads();
  float acc = bc1[t];
  #pragma unroll 4
  for (int k = 0; k < 256; k++) acc += p[k]*Wc1[k*H + t];
  float h = fmaxf(acc, 0.f)*Wc2[t];
  #pragma unroll
  for (int m = 1; m < 64; m <<= 1) h += __shfl_xor(h, m, 64);
  if ((t & 63) == 0) red[t>>6] = h;
  __syncthreads();
  if (t == 0) out[b] = red[0] + red[1] + bc2[0];
}

extern "C" void kernel_launch(void* const* d_in, const int* in_sizes, int n_in,
                              void* d_out, int out_size, void* d_ws, size_t ws_size,
                              hipStream_t stream){
  const float* x_fact = (const float*)d_in[0];
  const float* x_comp = (const float*)d_in[1];
  const float* ea_f2c = (const float*)d_in[2];
  const float* ea_c2f = (const float*)d_in[3];
  const int* s_f2c   = (const int*)d_in[4];
  const int* dst_f2c = (const int*)d_in[5];
  const int* s_c2f   = (const int*)d_in[6];
  const int* dst_c2f = (const int*)d_in[7];
  const int* fb = (const int*)d_in[8];
  const int* cb = (const int*)d_in[9];
  const float* W_in_f = (const float*)d_in[10];
  const float* b_in_f = (const float*)d_in[11];
  const float* W_in_c = (const float*)d_in[12];
  const float* b_in_c = (const float*)d_in[13];
  const float* eW1 = (const float*)d_in[14]; const float* eb1 = (const float*)d_in[15];
  const float* eW2 = (const float*)d_in[16]; const float* eb2 = (const float*)d_in[17];
  const float* eW3 = (const float*)d_in[18]; const float* eb3 = (const float*)d_in[19];
  const float* W_rel = (const float*)d_in[20]; const float* b_rel = (const float*)d_in[21];
  const float* W_root = (const float*)d_in[22];
  const float* ln_s = (const float*)d_in[23]; const float* ln_b = (const float*)d_in[24];
  const float* Wc1 = (const float*)d_in[25]; const float* bc1 = (const float*)d_in[26];
  const float* Wc2 = (const float*)d_in[27]; const float* bc2 = (const float*)d_in[28];
  float* out = (float*)d_out;

  char* ws = (char*)d_ws;
  size_t off = 0;
  auto alloc = [&](size_t bytes)->char*{ char* p = ws + off; off = (off + bytes + 255) & ~(size_t)255; return p; };
  float* xf0   = (float*)alloc((size_t)NFACT*H*4);
  float* xf1   = (float*)alloc((size_t)NFACT*H*4);
  float* xc0   = (float*)alloc((size_t)NCOMP*H*4);
  float* xc1   = (float*)alloc((size_t)NCOMP*H*4);
  float* w_f2c = (float*)alloc((size_t)EDGES*4);
  float* w_c2f = (float*)alloc((size_t)EDGES*4);
  int4* ed_f2c = (int4*)alloc((size_t)EDGES*16);
  int4* ed_c2f = (int4*)alloc((size_t)EDGES*16);
  int* off_f2c = (int*)alloc((size_t)(NCOMP+1)*4);
  int* cur_f2c = (int*)alloc((size_t)NCOMP*4);
  int* off_c2f = (int*)alloc((size_t)(NFACT+1)*4);
  int* cur_c2f = (int*)alloc((size_t)NFACT*4);
  int* part    = (int*)alloc(128*4);
  float* pooled= (float*)alloc((size_t)BATCH*256*4);
  _Float16* wt_in = (_Float16*)alloc((size_t)49152*2);
  _Float16* wcat0 = (_Float16*)alloc((size_t)32768*2);
  _Float16* wcat1 = (_Float16*)alloc((size_t)32768*2);

  // --- weight prep + fused gates/histograms ---
  k_prep<<<448,256,0,stream>>>(W_in_f, W_rel, W_root, wt_in, wcat0, wcat1);
  hipMemsetAsync(cur_f2c, 0, NCOMP*4, stream);
  hipMemsetAsync(cur_c2f, 0, NFACT*4, stream);
  k_gate2<<<1024,256,0,stream>>>(ea_f2c, ea_c2f, dst_f2c, dst_c2f,
                                 cur_f2c, cur_c2f,
                                 eW1,eb1,eW2,eb2,eW3,eb3, w_f2c, w_c2f, EDGES);

  // --- scans ---
  {
    int nb = (NCOMP + 1023)/1024;
    k_scan1<<<nb,1024,0,stream>>>(cur_f2c, NCOMP, off_f2c, part);
    k_scan2<<<1,128,0,stream>>>(part, nb);
    k_scan3<<<nb,1024,0,stream>>>(off_f2c, NCOMP, part, EDGES);
  }
  {
    int nb = (NFACT + 1023)/1024;
    k_scan1<<<nb,1024,0,stream>>>(cur_c2f, NFACT, off_c2f, part);
    k_scan2<<<1,128,0,stream>>>(part, nb);
    k_scan3<<<nb,1024,0,stream>>>(off_c2f, NFACT, part, EDGES);
  }
  hipMemsetAsync(cur_f2c, 0, NCOMP*4, stream);
  hipMemsetAsync(cur_c2f, 0, NFACT*4, stream);
  k_fill2d<<<1024,256,0,stream>>>(s_f2c, dst_f2c, w_f2c, off_f2c, cur_f2c, ed_f2c,
                                  s_c2f, dst_c2f, w_c2f, off_c2f, cur_c2f, ed_c2f, EDGES);

  // --- input projections ---
  k_input_m<<<512,256,0,stream>>>(x_fact, wt_in, b_in_f, xf0);
  k_input_s<64,8><<<NCOMP/8,128,0,stream>>>(x_comp, W_in_c, b_in_c, xc0);

  // --- GNN layers ---
  const float* xf_p = xf0; const float* xc_p = xc0;
  float* xf_n = xf1; float* xc_n = xc1;
  for (int l = 0; l < 2; l++){
    const float* Wr0 = W_rel  + (size_t)(l*2+0)*H*H;
    const float* br0 = b_rel  + (size_t)(l*2+0)*H;
    const float* br1 = b_rel  + (size_t)(l*2+1)*H;
    const float* Wo0 = W_root + (size_t)(l*2+0)*H*H;
    const _Float16* wcat = (l == 0) ? wcat0 : wcat1;
    k_layer<4><<<NCOMP/4,128,0,stream>>>(xf_p, xc_p, off_f2c, ed_f2c,
                                         Wr0, br0, Wo0, ln_s + H, ln_b + H, xc_n);
    k_layer_m<<<(NTILE+3)/4,256,0,stream>>>(xc_p, xf_p, off_c2f, ed_c2f,
                                            wcat, br1, ln_s, ln_b, xf_n);
    const float* tf = xf_p; xf_p = xf_n; xf_n = (float*)tf;
    const float* tc = xc_p; xc_p = xc_n; xc_n = (float*)tc;
  }

  // --- pooling + head ---
  hipMemsetAsync(pooled, 0, (size_t)BATCH*256*4, stream);
  k_pool_acc<<<FBLK + CBLK,128,0,stream>>>(xf_p, xc_p, fb, cb, pooled);
  k_head<<<BATCH,128,0,stream>>>(pooled, fb, cb, Wc1, bc1, Wc2, bc2, out);
}

// Round 10
// 774.987 us; speedup vs baseline: 1.0369x; 1.0369x over previous
//
#include <hip/hip_runtime.h>
#include <math.h>

#define H 128
#define EDGES 500000
#define NFACT 100000
#define NCOMP 5000
#define BATCH 64
#define NTILE 6250   // NFACT/16
#define NFB 1563     // fact-side blocks (4 tiles of 16 rows each)
#define NCB 625      // comp-side blocks (2 units x 4 rows)

typedef _Float16 half8_t __attribute__((ext_vector_type(8)));
typedef float floatx4 __attribute__((ext_vector_type(4)));

__device__ inline short4 f4_to_h4(float4 v){
  union { short4 s; _Float16 h[4]; } u;
  u.h[0]=(_Float16)v.x; u.h[1]=(_Float16)v.y; u.h[2]=(_Float16)v.z; u.h[3]=(_Float16)v.w;
  return u.s;
}

// ----------------- CSR build -----------------
__global__ __launch_bounds__(1024) void k_scan1(const int* __restrict__ cnt, int n,
                                                int* __restrict__ offs, int* __restrict__ part){
  __shared__ int sh[1024];
  int tid = threadIdx.x;
  int i = blockIdx.x*1024 + tid;
  int v = (i < n) ? cnt[i] : 0;
  sh[tid] = v;
  __syncthreads();
  for (int d = 1; d < 1024; d <<= 1){
    int t = (tid >= d) ? sh[tid-d] : 0;
    __syncthreads();
    sh[tid] += t;
    __syncthreads();
  }
  if (i < n) offs[i] = sh[tid] - v;
  if (tid == 1023) part[blockIdx.x] = sh[1023];
}

__global__ void k_scan2(int* part, int nb){
  __shared__ int sh[128];
  int tid = threadIdx.x;
  int v = (tid < nb) ? part[tid] : 0;
  sh[tid] = v;
  __syncthreads();
  for (int d = 1; d < 128; d <<= 1){
    int t = (tid >= d) ? sh[tid-d] : 0;
    __syncthreads();
    sh[tid] += t;
    __syncthreads();
  }
  if (tid < nb) part[tid] = sh[tid] - v;
}

__global__ __launch_bounds__(1024) void k_scan3(int* offs, int n, const int* __restrict__ part, int total){
  int i = blockIdx.x*1024 + threadIdx.x;
  if (i < n) offs[i] += part[blockIdx.x];
  if (i == 0) offs[n] = total;
}

// both directions in one launch, block-uniform direction split
__global__ void k_fill2d(const int* __restrict__ src0, const int* __restrict__ dst0,
                         const float* __restrict__ w0, const int* __restrict__ offs0,
                         int* __restrict__ cur0, int4* __restrict__ ed0,
                         const int* __restrict__ src1, const int* __restrict__ dst1,
                         const float* __restrict__ w1, const int* __restrict__ offs1,
                         int* __restrict__ cur1, int4* __restrict__ ed1, int n){
  int half = gridDim.x >> 1;
  int dir = blockIdx.x >= half;
  const int* src = dir ? src1 : src0;
  const int* dst = dir ? dst1 : dst0;
  const float* w = dir ? w1 : w0;
  const int* offs = dir ? offs1 : offs0;
  int* cur = dir ? cur1 : cur0;
  int4* ed = dir ? ed1 : ed0;
  int bid = blockIdx.x - (dir ? half : 0);
  for (int e = bid*blockDim.x + threadIdx.x; e < n; e += half*blockDim.x){
    int d = dst[e];
    int p = offs[d] + atomicAdd(&cur[d], 1);
    ed[p] = make_int4(src[e], __float_as_int(w[e]), d, 0);
  }
}

// ----------------- weight prep: f16 transposed copies -----------------
__global__ __launch_bounds__(256) void k_prep(const float* __restrict__ W_in,
                                              const float* __restrict__ W_rel,
                                              const float* __restrict__ W_root,
                                              _Float16* __restrict__ wt_in,
                                              _Float16* __restrict__ wcat0,
                                              _Float16* __restrict__ wcat1){
  int i = blockIdx.x*256 + threadIdx.x;
  if (i < 49152){
    int n = i / 384, k = i % 384;
    wt_in[i] = (_Float16)W_in[k*128 + n];
  } else if (i < 49152 + 32768){
    int j = i - 49152;
    int n = j / 256, k = j % 256;
    const float* Wr = W_rel  + 1*16384;
    const float* Wo = W_root + 1*16384;
    wcat0[j] = (_Float16)(k < 128 ? Wr[k*128+n] : Wo[(k-128)*128+n]);
  } else if (i < 49152 + 65536){
    int j = i - 49152 - 32768;
    int n = j / 256, k = j % 256;
    const float* Wr = W_rel  + 3*16384;
    const float* Wo = W_root + 3*16384;
    wcat1[j] = (_Float16)(k < 128 ? Wr[k*128+n] : Wo[(k-128)*128+n]);
  }
}

// ----------------- edge gate MLP + histogram (fused, R7-proven) -------------
__global__ __launch_bounds__(256) void k_gate2(const float* __restrict__ ea0,
                       const float* __restrict__ ea1,
                       const int* __restrict__ dst0, const int* __restrict__ dst1,
                       int* __restrict__ cnt0, int* __restrict__ cnt1,
                       const float* __restrict__ eW1, const float* __restrict__ eb1,
                       const float* __restrict__ eW2, const float* __restrict__ eb2,
                       const float* __restrict__ eW3, const float* __restrict__ eb3,
                       float* __restrict__ wout0, float* __restrict__ wout1, int n){
  __shared__ float w1t[32*12];   // transposed + padded: w1t[i][k] = eW1[k*32+i]
  __shared__ float w2s[32*16];
  __shared__ float b1s[32], b2s[16], w3s[16];
  __shared__ float b3s;
  int tid = threadIdx.x;
  for (int i = tid; i < 352; i += 256){
    int k = i >> 5, c = i & 31;
    w1t[c*12 + k] = eW1[i];
  }
  if (tid < 32) w1t[tid*12 + 11] = 0.f;
  for (int i = tid; i < 512; i += 256) w2s[i] = eW2[i];
  if (tid < 32) b1s[tid] = eb1[tid];
  if (tid < 16) b2s[tid] = eb2[tid];
  if (tid < 16) w3s[tid] = eW3[tid];
  if (tid == 0) b3s = eb3[0];
  __syncthreads();

  int half = gridDim.x >> 1;
  int dir = blockIdx.x >= half;
  const float* ea = dir ? ea1 : ea0;
  const int* dst  = dir ? dst1 : dst0;
  int* cnt        = dir ? cnt1 : cnt0;
  float* wout     = dir ? wout1 : wout0;
  int bid = blockIdx.x - (dir ? half : 0);

  const float4* w1t4 = (const float4*)w1t;
  const float4* w24  = (const float4*)w2s;
  float4 b2v0 = ((const float4*)b2s)[0], b2v1 = ((const float4*)b2s)[1];
  float4 b2v2 = ((const float4*)b2s)[2], b2v3 = ((const float4*)b2s)[3];
  float4 w3v0 = ((const float4*)w3s)[0], w3v1 = ((const float4*)w3s)[1];
  float4 w3v2 = ((const float4*)w3s)[2], w3v3 = ((const float4*)w3s)[3];

  for (int e = bid*blockDim.x + tid; e < n; e += half*blockDim.x){
    float2 eav = ((const float2*)ea)[e];
    float sent  = fminf(fmaxf(eav.x, -1.f), 1.f);
    float decay = eav.y;
    float dt = fmaxf(-__logf(fmaxf(decay, 1e-6f)) * 100.f, 0.f);
    float ds = fminf(dt * (1.f/30.f), 12.f);
    float s1 = __sinf(ds), c1 = __cosf(ds);
    float s2v = 2.f*s1*c1;
    float c2v = 1.f - 2.f*s1*s1;
    float s3v = s1*c2v + c1*s2v;
    float c3v = c1*c2v - s1*s2v;
    float s4v = 2.f*s2v*c2v;
    float c4v = 1.f - 2.f*s2v*s2v;
    float4 x0 = make_float4(sent, __logf(1.f + dt), s1, s2v);
    float4 x1 = make_float4(s3v, s4v, c1, c2v);
    float4 x2 = make_float4(c3v, c4v, ds, 0.f);

    float4 sa = b2v0, sb = b2v1, sc = b2v2, sd = b2v3;
    #pragma unroll 2
    for (int i = 0; i < 32; i++){
      float4 wa = w1t4[i*3+0], wb = w1t4[i*3+1], wc = w1t4[i*3+2];
      float h = b1s[i];
      h += x0.x*wa.x + x0.y*wa.y + x0.z*wa.z + x0.w*wa.w;
      h += x1.x*wb.x + x1.y*wb.y + x1.z*wb.z + x1.w*wb.w;
      h += x2.x*wc.x + x2.y*wc.y + x2.z*wc.z;
      h = fmaxf(h, 0.f);
      float4 va = w24[i*4+0], vb = w24[i*4+1], vc = w24[i*4+2], vd = w24[i*4+3];
      sa.x += h*va.x; sa.y += h*va.y; sa.z += h*va.z; sa.w += h*va.w;
      sb.x += h*vb.x; sb.y += h*vb.y; sb.z += h*vb.z; sb.w += h*vb.w;
      sc.x += h*vc.x; sc.y += h*vc.y; sc.z += h*vc.z; sc.w += h*vc.w;
      sd.x += h*vd.x; sd.y += h*vd.y; sd.z += h*vd.z; sd.w += h*vd.w;
    }
    float o = b3s;
    o += fmaxf(sa.x,0.f)*w3v0.x + fmaxf(sa.y,0.f)*w3v0.y + fmaxf(sa.z,0.f)*w3v0.z + fmaxf(sa.w,0.f)*w3v0.w;
    o += fmaxf(sb.x,0.f)*w3v1.x + fmaxf(sb.y,0.f)*w3v1.y + fmaxf(sb.z,0.f)*w3v1.z + fmaxf(sb.w,0.f)*w3v1.w;
    o += fmaxf(sc.x,0.f)*w3v2.x + fmaxf(sc.y,0.f)*w3v2.y + fmaxf(sc.z,0.f)*w3v2.z + fmaxf(sc.w,0.f)*w3v2.w;
    o += fmaxf(sd.x,0.f)*w3v3.x + fmaxf(sd.y,0.f)*w3v3.y + fmaxf(sd.z,0.f)*w3v3.z + fmaxf(sd.w,0.f)*w3v3.w;
    wout[e] = __fdividef(1.f, 1.f + __expf(-o));
    atomicAdd(&cnt[dst[e]], 1);
  }
}

// ----------------- simple input projection (comp side, small) -----------------
template<int K, int R>
__global__ __launch_bounds__(128) void k_input_s(const float* __restrict__ X, const float* __restrict__ W,
                                                 const float* __restrict__ bias, float* __restrict__ Y){
  __shared__ float xs[R*K];
  int t = threadIdx.x;
  long row0 = (long)blockIdx.x * R;
  const float4* src = (const float4*)(X + row0*K);
  float4* d4 = (float4*)xs;
  for (int i = t; i < R*K/4; i += 128) d4[i] = src[i];
  __syncthreads();
  float acc[R];
  #pragma unroll
  for (int r = 0; r < R; r++) acc[r] = 0.f;
  for (int k4 = 0; k4 < K/4; k4++){
    int kb = k4*4;
    float w0 = W[(kb+0)*H+t], w1 = W[(kb+1)*H+t], w2 = W[(kb+2)*H+t], w3 = W[(kb+3)*H+t];
    #pragma unroll
    for (int r = 0; r < R; r++){
      float4 xv = ((const float4*)(xs + r*K))[k4];
      acc[r] += xv.x*w0 + xv.y*w1 + xv.z*w2 + xv.w*w3;
    }
  }
  float b = bias[t];
  #pragma unroll
  for (int r = 0; r < R; r++)
    Y[(row0+r)*H + t] = fmaxf(acc[r] + b, 0.f);
}

// ----------------- MFMA input projection v5 (R4-proven) ---------------------
__global__ __launch_bounds__(256, 2) void k_input_m(const float* __restrict__ X,
                                                 const _Float16* __restrict__ Wt,
                                                 const float* __restrict__ bias,
                                                 float* __restrict__ Y){
  __shared__ _Float16 xs[16][392];
  __shared__ float tb[4*16*36];    // per-wave transpose buffers
  int t = threadIdx.x;
  int lane = t & 63, wv = t >> 6;
  int m = lane & 15, q = lane >> 4;

  half8_t wreg[2][12];
  float bcol[2];
  #pragma unroll
  for (int j = 0; j < 2; j++){
    int col = (wv*2 + j)*16 + m;
    const _Float16* wb = Wt + (size_t)col*384 + q*8;
    #pragma unroll
    for (int ks = 0; ks < 12; ks++) wreg[j][ks] = *(const half8_t*)(wb + ks*32);
    bcol[j] = bias[col];
  }

  int row_i[6], c4_i[6];
  #pragma unroll
  for (int i = 0; i < 6; i++){
    int idx = i*256 + t;
    row_i[i] = idx/96; c4_i[i] = idx - row_i[i]*96;
  }

  int tpb = (NTILE + gridDim.x - 1)/gridDim.x;
  int tb0 = blockIdx.x*tpb, tb1 = tb0 + tpb;
  if (tb1 > NTILE) tb1 = NTILE;
  if (tb0 >= tb1) return;

  const float4* X4 = (const float4*)X;
  float4 r[6];
  #pragma unroll
  for (int i = 0; i < 6; i++) r[i] = X4[(size_t)tb0*1536 + i*256 + t];

  float* tbw = &tb[wv*576];
  int rowl = lane >> 2, c8l = lane & 3;

  for (int tile = tb0; tile < tb1; ++tile){
    __syncthreads();
    #pragma unroll
    for (int i = 0; i < 6; i++)
      *(short4*)&xs[row_i[i]][c4_i[i]*4] = f4_to_h4(r[i]);
    __syncthreads();
    if (tile + 1 < tb1){
      size_t base = (size_t)(tile+1)*1536;
      #pragma unroll
      for (int i = 0; i < 6; i++) r[i] = X4[base + i*256 + t];
    }
    __builtin_amdgcn_sched_barrier(0);

    floatx4 acc0 = (floatx4){0.f,0.f,0.f,0.f};
    floatx4 acc1 = (floatx4){0.f,0.f,0.f,0.f};
    #pragma unroll
    for (int ks = 0; ks < 12; ks++){
      half8_t av = *(const half8_t*)&xs[m][ks*32 + q*8];
      acc0 = __builtin_amdgcn_mfma_f32_16x16x32_f16(av, wreg[0][ks], acc0, 0, 0, 0);
      acc1 = __builtin_amdgcn_mfma_f32_16x16x32_f16(av, wreg[1][ks], acc1, 0, 0, 0);
    }
    long rb = (long)tile*16;
    #pragma unroll
    for (int j = 0; j < 2; j++){
      floatx4 a = j ? acc1 : acc0;
      int lc = j*16 + m;
      #pragma unroll
      for (int i2 = 0; i2 < 4; i2++)
        tbw[(q*4+i2)*36 + lc] = fmaxf(a[i2] + bcol[j], 0.f);
    }
    __syncthreads();
    {
      const float* srcp = tbw + rowl*36 + c8l*8;
      float* dstp = Y + (rb + rowl)*H + wv*32 + c8l*8;
      *(float4*)dstp       = *(const float4*)(srcp);
      *(float4*)(dstp + 4) = *(const float4*)(srcp + 4);
    }
  }
}

// ----------------- FUSED GNN layer: fact (MFMA) + comp (fp32) in one launch -
// R10: k_layer (comp) and k_layer_m (fact) have disjoint read/write sets
// within a layer -> fuse via block-range partition (k_gate2/k_fill2d pattern).
// Comp work fills the fact side's latency bubbles (VALUBusy was 15%); serial
// sum (90+~45 us) -> ~max. Fact blocks first (critical path). Fact body =
// R8's proven v2 inner loop in 4-wave form (R9's prefetch reverted: -5us).
// Comp body = proven k_layer<4> as 2x128-thread units (it has NO barriers —
// every 32-lane group touches only its own xin rows).
__global__ __launch_bounds__(256) void k_layer_fused(
    const float* __restrict__ xf_p, const float* __restrict__ xc_p,
    const int* __restrict__ offs_c, const int4* __restrict__ ed_c,
    const float* __restrict__ Wrel, const float* __restrict__ brc,
    const float* __restrict__ Wroot,
    const float* __restrict__ lnsC, const float* __restrict__ lnbC,
    float* __restrict__ xc_n,
    const int* __restrict__ offs_f, const int4* __restrict__ ed_f,
    const _Float16* __restrict__ Wt, const float* __restrict__ brf,
    const float* __restrict__ lnsF, const float* __restrict__ lnbF,
    float* __restrict__ xf_n){
  __shared__ __align__(16) float smemf[9216];   // 36864 B
  int t = threadIdx.x;
  if ((int)blockIdx.x < NFB){
    // ================= fact side: 4 waves x 16-row tiles =================
    int lane = t & 63, wv = t >> 6;
    long tile = (long)blockIdx.x*4 + wv;
    if (tile >= NTILE) return;
    long row0 = tile*16;
    float* tb = smemf + wv*2304;
    _Float16 (*xin)[264] = reinterpret_cast<_Float16 (*)[264]>(tb);
    int c = lane & 31, g = lane >> 5;
    int grow0 = g*8;
    #pragma unroll
    for (int j = 0; j < 8; j++){
      int lr = grow0 + j;
      ((short4*)&xin[lr][0])[c] = make_short4(0,0,0,0);
      float4 pv = ((const float4*)(xf_p + (row0+lr)*H))[c];
      ((short4*)&xin[lr][128])[c] = f4_to_h4(pv);
    }
    int lo = offs_f[row0 + grow0], hi = offs_f[row0 + grow0 + 8];
    float4 a = make_float4(0.f,0.f,0.f,0.f);
    int cur = (int)row0 + grow0;
    int idx = lo;
    for (; idx + 8 <= hi; idx += 8){
      int4 rec[8];
      #pragma unroll
      for (int j = 0; j < 8; j++) rec[j] = ed_f[idx+j];
      float4 v[8];
      #pragma unroll
      for (int j = 0; j < 8; j++) v[j] = ((const float4*)(xc_p + (long)rec[j].x*H))[c];
      #pragma unroll
      for (int j = 0; j < 8; j++){
        float w = __int_as_float(rec[j].y);
        if (rec[j].z != cur){ ((short4*)&xin[cur-(int)row0][0])[c] = f4_to_h4(a); a = make_float4(0.f,0.f,0.f,0.f); cur = rec[j].z; }
        a.x += v[j].x*w; a.y += v[j].y*w; a.z += v[j].z*w; a.w += v[j].w*w;
      }
    }
    for (; idx < hi; idx++){
      int4 rec = ed_f[idx];
      float4 v = ((const float4*)(xc_p + (long)rec.x*H))[c];
      float w = __int_as_float(rec.y);
      if (rec.z != cur){ ((short4*)&xin[cur-(int)row0][0])[c] = f4_to_h4(a); a = make_float4(0.f,0.f,0.f,0.f); cur = rec.z; }
      a.x += v.x*w; a.y += v.y*w; a.z += v.z*w; a.w += v.w*w;
    }
    if (lo < hi) ((short4*)&xin[cur-(int)row0][0])[c] = f4_to_h4(a);

    int m = lane & 15, q = lane >> 4;
    floatx4 acc[8];
    #pragma unroll
    for (int nt = 0; nt < 8; nt++) acc[nt] = (floatx4){0.f,0.f,0.f,0.f};
    #pragma unroll
    for (int ks = 0; ks < 8; ks++){
      half8_t av = *(const half8_t*)&xin[m][ks*32 + q*8];
      #pragma unroll
      for (int nt = 0; nt < 8; nt++){
        half8_t bv = *(const half8_t*)(Wt + (size_t)(nt*16 + m)*256 + ks*32 + q*8);
        acc[nt] = __builtin_amdgcn_mfma_f32_16x16x32_f16(av, bv, acc[nt], 0, 0, 0);
      }
    }
    float vs[8][4];
    float s[4] = {0.f,0.f,0.f,0.f}, ss[4] = {0.f,0.f,0.f,0.f};
    #pragma unroll
    for (int nt = 0; nt < 8; nt++){
      int col = nt*16 + m;
      float b = brf[col];
      #pragma unroll
      for (int i = 0; i < 4; i++){
        int lr = q*4 + i;
        float pv = (float)xin[lr][128 + col];
        float v = fmaxf(acc[nt][i] + b, 0.f) + pv;
        vs[nt][i] = v;
        s[i] += v; ss[i] += v*v;
      }
    }
    #pragma unroll
    for (int i = 0; i < 4; i++){
      #pragma unroll
      for (int mm = 1; mm < 16; mm <<= 1){
        s[i]  += __shfl_xor(s[i],  mm, 64);
        ss[i] += __shfl_xor(ss[i], mm, 64);
      }
    }
    asm volatile("" ::: "memory");   // xin fully consumed -> reuse LDS as tb
    #pragma unroll
    for (int nt = 0; nt < 8; nt++){
      int col = nt*16 + m;
      float lsc = lnsF[col], lbi = lnbF[col];
      int chnk = col >> 5, lc = col & 31;
      #pragma unroll
      for (int i = 0; i < 4; i++){
        float mu  = s[i]*(1.f/H);
        float var = ss[i]*(1.f/H) - mu*mu;
        float rstd = rsqrtf(var + 1e-5f);
        tb[(q*4+i)*144 + chnk*36 + lc] = (vs[nt][i] - mu)*rstd*lsc + lbi;
      }
    }
    asm volatile("" ::: "memory");
    {
      int rowl = lane >> 2, c8 = lane & 3;
      const float* srcp = &tb[rowl*144 + c8*36];
      float4* dst4 = (float4*)(xf_n + (row0 + rowl)*H + c8*32);
      #pragma unroll
      for (int k = 0; k < 8; k++)
        dst4[k] = *(const float4*)(srcp + k*4);
    }
  } else {
    // ================= comp side: 2 x 128-thread R=4 units ===============
    int unit = t >> 7, tt = t & 127;
    int ctile = ((int)blockIdx.x - NFB)*2 + unit;
    float (*xin)[256] = (float(*)[256])(smemf + unit*1024);
    int c = tt & 31, g = tt >> 5;     // g in 0..3, one row per group
    long row0 = (long)ctile * 4;
    {
      ((float4*)&xin[g][0])[c] = make_float4(0.f,0.f,0.f,0.f);
      ((float4*)&xin[g][128])[c] = ((const float4*)(xc_p + (row0+g)*H))[c];
    }
    int lo = offs_c[row0 + g], hi = offs_c[row0 + g + 1];
    float4 a = make_float4(0.f,0.f,0.f,0.f);
    int cur = (int)row0 + g;
    int idx = lo;
    for (; idx + 8 <= hi; idx += 8){
      int4 rec[8];
      #pragma unroll
      for (int j = 0; j < 8; j++) rec[j] = ed_c[idx+j];
      float4 v[8];
      #pragma unroll
      for (int j = 0; j < 8; j++) v[j] = ((const float4*)(xf_p + (long)rec[j].x*H))[c];
      #pragma unroll
      for (int j = 0; j < 8; j++){
        float w = __int_as_float(rec[j].y);
        if (rec[j].z != cur){ ((float4*)&xin[cur-(int)row0][0])[c] = a; a = make_float4(0.f,0.f,0.f,0.f); cur = rec[j].z; }
        a.x += v[j].x*w; a.y += v[j].y*w; a.z += v[j].z*w; a.w += v[j].w*w;
      }
    }
    for (; idx < hi; idx++){
      int4 rec = ed_c[idx];
      float4 v = ((const float4*)(xf_p + (long)rec.x*H))[c];
      float w = __int_as_float(rec.y);
      if (rec.z != cur){ ((float4*)&xin[cur-(int)row0][0])[c] = a; a = make_float4(0.f,0.f,0.f,0.f); cur = rec.z; }
      a.x += v.x*w; a.y += v.y*w; a.z += v.z*w; a.w += v.w*w;
    }
    if (lo < hi) ((float4*)&xin[cur-(int)row0][0])[c] = a;

    float4 acc = ((const float4*)brc)[c];
    #pragma unroll
    for (int p = 0; p < 2; p++){
      const float4* Wp = (const float4*)(p ? Wroot : Wrel) + c;
      #pragma unroll 4
      for (int k4 = 0; k4 < 32; k4++){
        float4 xv = ((const float4*)xin[g])[p*32 + k4];
        #pragma unroll
        for (int kk = 0; kk < 4; kk++){
          float4 wv = Wp[(size_t)(k4*4+kk)*32];
          float xk = (kk==0) ? xv.x : (kk==1) ? xv.y : (kk==2) ? xv.z : xv.w;
          acc.x += xk*wv.x; acc.y += xk*wv.y; acc.z += xk*wv.z; acc.w += xk*wv.w;
        }
      }
    }
    float4 lsc = ((const float4*)lnsC)[c];
    float4 lbi = ((const float4*)lnbC)[c];
    {
      float4 pv = ((const float4*)&xin[g][128])[c];
      float4 v;
      v.x = fmaxf(acc.x, 0.f) + pv.x;
      v.y = fmaxf(acc.y, 0.f) + pv.y;
      v.z = fmaxf(acc.z, 0.f) + pv.z;
      v.w = fmaxf(acc.w, 0.f) + pv.w;
      float s  = v.x + v.y + v.z + v.w;
      float ss = v.x*v.x + v.y*v.y + v.z*v.z + v.w*v.w;
      #pragma unroll
      for (int mm = 1; mm < 32; mm <<= 1){ s += __shfl_xor(s, mm, 64); ss += __shfl_xor(ss, mm, 64); }
      float mu  = s*(1.f/H);
      float var = ss*(1.f/H) - mu*mu;
      float rstd = rsqrtf(var + 1e-5f);
      float4 o;
      o.x = (v.x - mu)*rstd*lsc.x + lbi.x;
      o.y = (v.y - mu)*rstd*lsc.y + lbi.y;
      o.z = (v.z - mu)*rstd*lsc.z + lbi.z;
      o.w = (v.w - mu)*rstd*lsc.w + lbi.w;
      ((float4*)(xc_n + (row0+g)*H))[c] = o;
    }
  }
}

// ----------------- pooling -----------------
#define PCHUNK 128
#define FBLK ((NFACT + PCHUNK - 1) / PCHUNK)
#define CBLK ((NCOMP + PCHUNK - 1) / PCHUNK)

__global__ __launch_bounds__(128) void k_pool_acc(const float* __restrict__ xf, const float* __restrict__ xc,
                                                  const int* __restrict__ fb, const int* __restrict__ cb,
                                                  float* __restrict__ pooled){
  int t = threadIdx.x;
  int b = blockIdx.x;
  if (b < FBLK){
    int start = b*PCHUNK, end = start + PCHUNK; if (end > NFACT) end = NFACT;
    float s = 0.f; int curb = -1;
    for (int i = start; i < end; i++){
      int bb = fb[i];
      if (bb != curb){
        if (curb >= 0) atomicAdd(&pooled[curb*256 + t], s);
        curb = bb; s = 0.f;
      }
      s += xf[(long)i*H + t];
    }
    if (curb >= 0) atomicAdd(&pooled[curb*256 + t], s);
  } else {
    int bbk = b - FBLK;
    int start = bbk*PCHUNK, end = start + PCHUNK; if (end > NCOMP) end = NCOMP;
    float s = 0.f; int curb = -1;
    for (int i = start; i < end; i++){
      int bb = cb[i];
      if (bb != curb){
        if (curb >= 0) atomicAdd(&pooled[curb*256 + 128 + t], s);
        curb = bb; s = 0.f;
      }
      s += xc[(long)i*H + t];
    }
    if (curb >= 0) atomicAdd(&pooled[curb*256 + 128 + t], s);
  }
}

// ----------------- classifier head -----------------
__device__ inline int lowerb(const int* a, int n, int key){
  int lo = 0, hi = n;
  while (lo < hi){ int m = (lo+hi) >> 1; if (a[m] < key) lo = m+1; else hi = m; }
  return lo;
}

__global__ __launch_bounds__(128) void k_head(const float* __restrict__ pooled,
                                              const int* __restrict__ fb, const int* __restrict__ cb,
                                              const float* __restrict__ Wc1, const float* __restrict__ bc1,
                                              const float* __restrict__ Wc2, const float* __restrict__ bc2,
                                              float* __restrict__ out){
  __shared__ float p[256];
  __shared__ float red[2];
  int t = threadIdx.x, b = blockIdx.x;
  int flo = lowerb(fb, NFACT, b), fhi = lowerb(fb, NFACT, b+1);
  int clo = lowerb(cb, NCOMP, b), chi = lowerb(cb, NCOMP, b+1);
  float fc = (float)((fhi - flo) > 1 ? (fhi - flo) : 1);
  float cc = (float)((chi - clo) > 1 ? (chi - clo) : 1);
  p[t]       = pooled[b*256 + t] / fc;
  p[128 + t] = pooled[b*256 + 128 + t] / cc;
  __syncthreads();
  float acc = bc1[t];
  #pragma unroll 4
  for (int k = 0; k < 256; k++) acc += p[k]*Wc1[k*H + t];
  float h = fmaxf(acc, 0.f)*Wc2[t];
  #pragma unroll
  for (int m = 1; m < 64; m <<= 1) h += __shfl_xor(h, m, 64);
  if ((t & 63) == 0) red[t>>6] = h;
  __syncthreads();
  if (t == 0) out[b] = red[0] + red[1] + bc2[0];
}

extern "C" void kernel_launch(void* const* d_in, const int* in_sizes, int n_in,
                              void* d_out, int out_size, void* d_ws, size_t ws_size,
                              hipStream_t stream){
  const float* x_fact = (const float*)d_in[0];
  const float* x_comp = (const float*)d_in[1];
  const float* ea_f2c = (const float*)d_in[2];
  const float* ea_c2f = (const float*)d_in[3];
  const int* s_f2c   = (const int*)d_in[4];
  const int* dst_f2c = (const int*)d_in[5];
  const int* s_c2f   = (const int*)d_in[6];
  const int* dst_c2f = (const int*)d_in[7];
  const int* fb = (const int*)d_in[8];
  const int* cb = (const int*)d_in[9];
  const float* W_in_f = (const float*)d_in[10];
  const float* b_in_f = (const float*)d_in[11];
  const float* W_in_c = (const float*)d_in[12];
  const float* b_in_c = (const float*)d_in[13];
  const float* eW1 = (const float*)d_in[14]; const float* eb1 = (const float*)d_in[15];
  const float* eW2 = (const float*)d_in[16]; const float* eb2 = (const float*)d_in[17];
  const float* eW3 = (const float*)d_in[18]; const float* eb3 = (const float*)d_in[19];
  const float* W_rel = (const float*)d_in[20]; const float* b_rel = (const float*)d_in[21];
  const float* W_root = (const float*)d_in[22];
  const float* ln_s = (const float*)d_in[23]; const float* ln_b = (const float*)d_in[24];
  const float* Wc1 = (const float*)d_in[25]; const float* bc1 = (const float*)d_in[26];
  const float* Wc2 = (const float*)d_in[27]; const float* bc2 = (const float*)d_in[28];
  float* out = (float*)d_out;

  char* ws = (char*)d_ws;
  size_t off = 0;
  auto alloc = [&](size_t bytes)->char*{ char* p = ws + off; off = (off + bytes + 255) & ~(size_t)255; return p; };
  float* xf0   = (float*)alloc((size_t)NFACT*H*4);
  float* xf1   = (float*)alloc((size_t)NFACT*H*4);
  float* xc0   = (float*)alloc((size_t)NCOMP*H*4);
  float* xc1   = (float*)alloc((size_t)NCOMP*H*4);
  float* w_f2c = (float*)alloc((size_t)EDGES*4);
  float* w_c2f = (float*)alloc((size_t)EDGES*4);
  int4* ed_f2c = (int4*)alloc((size_t)EDGES*16);
  int4* ed_c2f = (int4*)alloc((size_t)EDGES*16);
  int* off_f2c = (int*)alloc((size_t)(NCOMP+1)*4);
  int* cur_f2c = (int*)alloc((size_t)NCOMP*4);
  int* off_c2f = (int*)alloc((size_t)(NFACT+1)*4);
  int* cur_c2f = (int*)alloc((size_t)NFACT*4);
  int* part    = (int*)alloc(128*4);
  float* pooled= (float*)alloc((size_t)BATCH*256*4);
  _Float16* wt_in = (_Float16*)alloc((size_t)49152*2);
  _Float16* wcat0 = (_Float16*)alloc((size_t)32768*2);
  _Float16* wcat1 = (_Float16*)alloc((size_t)32768*2);

  // --- weight prep + fused gates/histograms ---
  k_prep<<<448,256,0,stream>>>(W_in_f, W_rel, W_root, wt_in, wcat0, wcat1);
  hipMemsetAsync(cur_f2c, 0, NCOMP*4, stream);
  hipMemsetAsync(cur_c2f, 0, NFACT*4, stream);
  k_gate2<<<1024,256,0,stream>>>(ea_f2c, ea_c2f, dst_f2c, dst_c2f,
                                 cur_f2c, cur_c2f,
                                 eW1,eb1,eW2,eb2,eW3,eb3, w_f2c, w_c2f, EDGES);

  // --- scans ---
  {
    int nb = (NCOMP + 1023)/1024;
    k_scan1<<<nb,1024,0,stream>>>(cur_f2c, NCOMP, off_f2c, part);
    k_scan2<<<1,128,0,stream>>>(part, nb);
    k_scan3<<<nb,1024,0,stream>>>(off_f2c, NCOMP, part, EDGES);
  }
  {
    int nb = (NFACT + 1023)/1024;
    k_scan1<<<nb,1024,0,stream>>>(cur_c2f, NFACT, off_c2f, part);
    k_scan2<<<1,128,0,stream>>>(part, nb);
    k_scan3<<<nb,1024,0,stream>>>(off_c2f, NFACT, part, EDGES);
  }
  hipMemsetAsync(cur_f2c, 0, NCOMP*4, stream);
  hipMemsetAsync(cur_c2f, 0, NFACT*4, stream);
  k_fill2d<<<1024,256,0,stream>>>(s_f2c, dst_f2c, w_f2c, off_f2c, cur_f2c, ed_f2c,
                                  s_c2f, dst_c2f, w_c2f, off_c2f, cur_c2f, ed_c2f, EDGES);

  // --- input projections ---
  k_input_m<<<512,256,0,stream>>>(x_fact, wt_in, b_in_f, xf0);
  k_input_s<64,8><<<NCOMP/8,128,0,stream>>>(x_comp, W_in_c, b_in_c, xc0);

  // --- GNN layers: one fused dispatch per layer ---
  const float* xf_p = xf0; const float* xc_p = xc0;
  float* xf_n = xf1; float* xc_n = xc1;
  for (int l = 0; l < 2; l++){
    const float* Wr0 = W_rel  + (size_t)(l*2+0)*H*H;
    const float* br0 = b_rel  + (size_t)(l*2+0)*H;
    const float* br1 = b_rel  + (size_t)(l*2+1)*H;
    const float* Wo0 = W_root + (size_t)(l*2+0)*H*H;
    const _Float16* wcat = (l == 0) ? wcat0 : wcat1;
    k_layer_fused<<<NFB + NCB,256,0,stream>>>(
        xf_p, xc_p, off_f2c, ed_f2c, Wr0, br0, Wo0, ln_s + H, ln_b + H, xc_n,
        off_c2f, ed_c2f, wcat, br1, ln_s, ln_b, xf_n);
    const float* tf = xf_p; xf_p = xf_n; xf_n = (float*)tf;
    const float* tc = xc_p; xc_p = xc_n; xc_n = (float*)tc;
  }

  // --- pooling + head ---
  hipMemsetAsync(pooled, 0, (size_t)BATCH*256*4, stream);
  k_pool_acc<<<FBLK + CBLK,128,0,stream>>>(xf_p, xc_p, fb, cb, pooled);
  k_head<<<BATCH,128,0,stream>>>(pooled, fb, cb, Wc1, bc1, Wc2, bc2, out);
}